// Round 6
// baseline (228.034 us; speedup 1.0000x reference)
//
#include <hip/hip_runtime.h>
#include <cfloat>
#include <stdint.h>

// VQ argmin via exact-split f16 MFMA GEMM — R26: 32x32x16 MFMA shape on the
// R25 clean base. R25 re-verified the barrier-free direct-global structure
// (gemm 120us, MfmaUtil 38%, atomicMin free; R24's poison was __threadfence's
// L2 invalidate; R23's was the 168-reg occupancy cliff). R26 swaps the MFMA
// shape: 24x v_mfma_f32_32x32x16_f16 per stage/wave instead of 48x 16x16x32
// (same FLOPs; m119: +17% FLOP/cyc, -50% MFMA issue slots). Same 16x 1KB
// coalesced fragment loads, same 64 AGPR acc (4x floatx16), same 4-pointer
// imm-offset addressing via re-layouted prep granules: A in 128-row (mh2)
// granules, A+B d-group q stored at bit-swapped slot sigma(q)=((q&1)<<1)|(q>>1)
// so lane addr = base + hi*gran + t*2048B + {mi,nj}*512B (all imm).
// C/D map: col=lane&31, row=(reg&3)+8*(reg>>2)+4*(lane>>5) [m74/m101 HW-
// verified]; A/B k = (lane>>5)*8+j (32-lane analog of the verified 16x16).
// Same 3-term split zh*eh + zh*el + zl*eh, dist = fp32(zsq - acc*2^-12),
// same u64 atomicMin reduction (ties impossible).
#define KC 8192
#define NQ 8192
#define DD 256
#define NSTAGE 8

typedef _Float16 f16;
typedef _Float16 half8 __attribute__((ext_vector_type(8)));
typedef float floatx16 __attribute__((ext_vector_type(16)));

// ---- workspace maps ----
#define WS_AH   0
#define WS_AL   4194304
#define WS_BH   8388608
#define WS_BL1  12582912           // 1-pass: Bh/Bl 4MB each
#define WS_KEY1 16777216
#define WS_NEED1 (16777216ull + 65536ull)   // 16.06 MiB (<= every observed ws)
#define WS_BL2  10485760           // 2-pass fallback: Bh/Bl 2MB each
#define WS_KEY2 12582912

// ---- device helpers ----
// B-prep: layout [ntl][s 8][sigma 4][n 128] rows of 8 halfs; d-group q stored
// at slot sigma(q) = ((q&1)<<1)|(q>>1) so the 32x32 GEMM reads slot 2*hi+t to
// get d-group 2*t+hi with immediate t-offsets. Same bytes per (n, d-group).
__device__ __forceinline__ void prep_b_body(const float* __restrict__ cb,
                                            f16* __restrict__ Bh, f16* __restrict__ Bl,
                                            int kofs, int gid) {
    int n = gid & 127;
    int q = (gid >> 7) & 3;
    int s = (gid >> 9) & 7;
    int ntl = gid >> 12;
    int K = kofs + ntl * 128 + n;
    int d0 = s * 32 + q * 8;
    const float4 v0 = *(const float4*)(cb + (size_t)K * DD + d0);
    const float4 v1 = *(const float4*)(cb + (size_t)K * DD + d0 + 4);
    float vv[8] = {v0.x, v0.y, v0.z, v0.w, v1.x, v1.y, v1.z, v1.w};
    half8 eh8, el8;
    #pragma unroll
    for (int j = 0; j < 8; ++j) {
        float e = vv[j] * 8192.0f;               // exact pow2 scale
        f16 h = (f16)e;
        eh8[j] = h;
        el8[j] = (f16)(e - (float)h);
    }
    int sig = ((q & 1) << 1) | (q >> 1);
    size_t og = ((size_t)(ntl * 8 + s) * 4 + sig) * 128 + n;
    *(half8*)(Bh + og * 8) = eh8;
    *(half8*)(Bl + og * 8) = el8;
}

// A-prep: layout [mh2 64][s 8][sigma 4][r 128] rows of 8 halfs (128-row
// granules keyed by mh2 = Q>>7), sigma-swapped d-group slots as for B.
// Same fragment bytes per (query, d-group) as all passers.
__device__ __forceinline__ void prep_a_vec_body(const float* __restrict__ z,
                                                f16* __restrict__ Ah, f16* __restrict__ Al,
                                                int bid, int tid) {
    const int mt = bid >> 3;
    const int s  = bid & 7;
    const int q  = tid >> 6;
    const int lane = tid & 63;
    const int r0 = lane * 4;
    const int Q0 = mt * 256;
    const int b = Q0 >> 10;
    const int t0 = (Q0 & 1023) + r0;
    const float* zp = z + (size_t)b * (DD * 1024) + t0;
    const int d0 = s * 32 + q * 8;
    float4 v[8];
    #pragma unroll
    for (int j = 0; j < 8; ++j)
        v[j] = *(const float4*)(zp + (size_t)(d0 + j) * 1024);
    const int sig = ((q & 1) << 1) | (q >> 1);
    const int mh2 = mt * 2 + (r0 >> 7);              // r0..r0+3 same 128-half
    const size_t gbase = ((size_t)(mh2 * 8 + s) * 4 + sig) * 128 + (r0 & 127);
    #pragma unroll
    for (int dq = 0; dq < 4; ++dq) {
        half8 zh8, zl8;
        #pragma unroll
        for (int j = 0; j < 8; ++j) {
            float vv = (dq == 0) ? v[j].x : (dq == 1) ? v[j].y : (dq == 2) ? v[j].z : v[j].w;
            f16 h = (f16)vv;
            zh8[j] = h;
            zl8[j] = (f16)(vv - (float)h);       // exact fp32 residual
        }
        *(half8*)(Ah + (gbase + dq) * 8) = zh8;
        *(half8*)(Al + (gbase + dq) * 8) = zl8;
    }
}

// zsq split across 2 threads/query (exact partial chains of all passers;
// zsq[q] = s0 + s1 identical). Also inits the atomic key array.
__device__ __forceinline__ void zsq2_body(const float* __restrict__ z,
                                          float* __restrict__ zsq,
                                          unsigned long long* __restrict__ key,
                                          int gid) {
    int q = gid >> 1, half = gid & 1;
    int b = q >> 10, t = q & 1023;
    const float* p = z + (size_t)b * (DD * 1024) + t + (size_t)(half * 128) * 1024;
    float s = 0.f;
    #pragma unroll 8
    for (int d = 0; d < 128; ++d) { float v = p[(size_t)d * 1024]; s = fmaf(v, v, s); }
    float so = __shfl_xor(s, 1, 64);             // partner half, same q
    if (half == 0) { zsq[q] = s + so; key[q] = ~0ull; }
}

// ---- fused prep, long poles first:
//   blocks [0,64) zsq+key-init | [64,320) A-vec | [320,1344) B ----
__global__ void vq_prep_all(const float* __restrict__ z, const float* __restrict__ cb,
                            f16* __restrict__ Ah, f16* __restrict__ Al,
                            f16* __restrict__ Bh, f16* __restrict__ Bl,
                            float* __restrict__ zsq, unsigned long long* __restrict__ key) {
    int bid = blockIdx.x;
    int tid = threadIdx.x;
    if (bid < 64) {
        zsq2_body(z, zsq, key, bid * 256 + tid);
    } else if (bid < 320) {
        prep_a_vec_body(z, Ah, Al, bid - 64, tid);
    } else {
        prep_b_body(cb, Bh, Bl, 0, (bid - 320) * 256 + tid);
    }
}

// standalone preps for the 2-pass fallback
__global__ void vq_prep_az(const float* __restrict__ z,
                           f16* __restrict__ Ah, f16* __restrict__ Al,
                           float* __restrict__ zsq, unsigned long long* __restrict__ key) {
    int bid = blockIdx.x;
    if (bid < 64) zsq2_body(z, zsq, key, bid * 256 + threadIdx.x);
    else          prep_a_vec_body(z, Ah, Al, bid - 64, threadIdx.x);
}
__global__ void vq_prep_b(const float* __restrict__ cb,
                          f16* __restrict__ Bh, f16* __restrict__ Bl, int kofs) {
    prep_b_body(cb, Bh, Bl, kofs, blockIdx.x * 256 + threadIdx.x);
}

// ---- main GEMM (R26): 128x128 block, 2x2 waves of 64x64 built from 2x2
//      v_mfma_f32_32x32x16_f16, A and B direct from global (16x 1KB coalesced
//      loads/stage/wave), NO barriers in the K-loop, acc = 4 x floatx16 =
//      64 AGPRs. Epilogue: fire-and-forget device-scope atomicMin. ----
__global__ __launch_bounds__(256, 4)
void vq_gemm32(const f16* __restrict__ Ah, const f16* __restrict__ Al,
               const f16* __restrict__ Bh, const f16* __restrict__ Bl,
               const float* __restrict__ zsq, unsigned long long* __restrict__ keyp,
               int kofs) {
    // Swizzle (R12/R21-verified): per XCD, 8-ntl B chunks x 8 mh2 A tiles.
    const int flat = blockIdx.x;
    const int xcd = flat & 7;
    const int idx = flat >> 3;
    const int mh2 = xcd * 8 + ((idx >> 3) & 7);     // 0..63, 128-row tile
    const int ntl = (idx >> 6) * 8 + (idx & 7);     // 0..63 / 0..31
    const int tid = threadIdx.x;
    const int lane = tid & 63;
    const int wv = tid >> 6;
    const int wm = wv >> 1, wn = wv & 1;            // 2x2 waves of 64x64
    const int hi = lane >> 5;                       // k-group half (0/1)
    const int l32 = lane & 31;

    __shared__ unsigned long long kbuf[256];        // epilogue merge only

    floatx16 acc[2][2];
    #pragma unroll
    for (int i = 0; i < 2; ++i)
        #pragma unroll
        for (int j = 0; j < 2; ++j) acc[i][j] = (floatx16)0.f;

    // Lane base addresses (halfs). Granule = 128 rows/cols x 8 halfs = 1024.
    //   A granule idx = (mh2*8+s)*4 + 2*hi + t ; row = wm*64 + mi*32 + l32
    //   B granule idx = (ntl*8+s)*4 + 2*hi + t ; col = wn*64 + nj*32 + l32
    // t*1024 halfs (2048B) and {mi,nj}*256 halfs (512B) are imm offsets.
    const f16* Ap  = Ah + ((size_t)(mh2 * 32 + 2 * hi)) * 1024
                        + (size_t)(wm * 64 + l32) * 8;
    const f16* Alp = Al + ((size_t)(mh2 * 32 + 2 * hi)) * 1024
                        + (size_t)(wm * 64 + l32) * 8;
    const f16* Bpb = Bh + ((size_t)(ntl * 32 + 2 * hi)) * 1024
                        + (size_t)(wn * 64 + l32) * 8;
    const f16* Blb = Bl + ((size_t)(ntl * 32 + 2 * hi)) * 1024
                        + (size_t)(wn * 64 + l32) * 8;

    for (int s = 0; s < NSTAGE; ++s) {
        // ---- 16 x 1KB coalesced fragment loads ----
        half8 a0[2][2], a1[2][2], b0[2][2], b1[2][2];   // [t][mi or nj]
        #pragma unroll
        for (int t = 0; t < 2; ++t)
            #pragma unroll
            for (int i = 0; i < 2; ++i) {
                a0[t][i] = *(const half8*)(Ap  + t * 1024 + i * 256);
                a1[t][i] = *(const half8*)(Alp + t * 1024 + i * 256);
                b0[t][i] = *(const half8*)(Bpb + t * 1024 + i * 256);
                b1[t][i] = *(const half8*)(Blb + t * 1024 + i * 256);
            }
        // ---- 24 x mfma_f32_32x32x16_f16 (3 terms x 2 t x 2x2 tiles) ----
        #pragma unroll
        for (int t = 0; t < 2; ++t)
            #pragma unroll
            for (int mi = 0; mi < 2; ++mi)
                #pragma unroll
                for (int nj = 0; nj < 2; ++nj)
                    acc[mi][nj] = __builtin_amdgcn_mfma_f32_32x32x16_f16(
                        a0[t][mi], b0[t][nj], acc[mi][nj], 0, 0, 0);
        #pragma unroll
        for (int t = 0; t < 2; ++t)
            #pragma unroll
            for (int mi = 0; mi < 2; ++mi)
                #pragma unroll
                for (int nj = 0; nj < 2; ++nj)
                    acc[mi][nj] = __builtin_amdgcn_mfma_f32_32x32x16_f16(
                        a0[t][mi], b1[t][nj], acc[mi][nj], 0, 0, 0);
        #pragma unroll
        for (int t = 0; t < 2; ++t)
            #pragma unroll
            for (int mi = 0; mi < 2; ++mi)
                #pragma unroll
                for (int nj = 0; nj < 2; ++nj)
                    acc[mi][nj] = __builtin_amdgcn_mfma_f32_32x32x16_f16(
                        a1[t][mi], b0[t][nj], acc[mi][nj], 0, 0, 0);
        // advance one K-stage: 4 granules = 4096 halfs for both A and B
        Ap += 4096; Alp += 4096; Bpb += 4096; Blb += 4096;
    }

    // ---- epilogue: C/D map col=l32, row=(reg&3)+8*(reg>>2)+4*hi [m74/m101];
    //      dist quantization + 32-lane butterfly + device-wide atomicMin ----
    const int kb = kofs + ntl * 128 + wn * 64;
    #pragma unroll
    for (int mi = 0; mi < 2; ++mi) {
        #pragma unroll
        for (int reg = 0; reg < 16; ++reg) {
            int qlocal = wm * 64 + mi * 32 + (reg & 3) + 8 * (reg >> 2) + 4 * hi;
            float zq = zsq[mh2 * 128 + qlocal];
            float bd = FLT_MAX; int bk = 0;
            #pragma unroll
            for (int nj = 0; nj < 2; ++nj) {        // ascending k: '<' keeps lowest
                float dd = zq - acc[mi][nj][reg] * 0x1p-12f;  // single fp32 rounding
                int kk = kb + nj * 32 + l32;
                if (dd < bd || (dd == bd && kk < bk)) { bd = dd; bk = kk; }
            }
            #pragma unroll
            for (int mm = 1; mm <= 16; mm <<= 1) {  // 32-lane butterfly, same q
                float od = __shfl_xor(bd, mm, 64);
                int ok = __shfl_xor(bk, mm, 64);
                if (od < bd || (od == bd && ok < bk)) { bd = od; bk = ok; }
            }
            if (l32 == 0)
                kbuf[wn * 128 + qlocal] =
                    ((unsigned long long)__float_as_uint(bd) << 32) | (unsigned int)bk;
        }
    }
    __syncthreads();
    if (tid < 128) {
        unsigned long long k0 = kbuf[tid];
        unsigned long long k1 = kbuf[128 + tid];
        unsigned long long key = (k1 < k0) ? k1 : k0;
        atomicMin(&keyp[mh2 * 128 + tid], key);     // fire-and-forget, no fence
    }
}

__global__ void vq_extract(const unsigned long long* __restrict__ key,
                           int* __restrict__ out) {
    int q = blockIdx.x * 256 + threadIdx.x;
    out[q] = (int)(key[q] & 0xFFFFFFFFull);
}

extern "C" void kernel_launch(void* const* d_in, const int* in_sizes, int n_in,
                              void* d_out, int out_size, void* d_ws, size_t ws_size,
                              hipStream_t stream) {
    const float* z  = (const float*)d_in[0];   // (8, 256, 1024) fp32
    const float* cb = (const float*)d_in[1];   // (8192, 256) fp32
    char* ws = (char*)d_ws;
    f16* Ah = (f16*)(ws + WS_AH);
    f16* Al = (f16*)(ws + WS_AL);
    // zsq parked in d_out (32 KB): read by gemm, overwritten by extract.
    float* zsq = (float*)d_out;
    int* out = (int*)d_out;

    if (ws_size >= WS_NEED1) {
        f16* Bh = (f16*)(ws + WS_BH);
        f16* Bl = (f16*)(ws + WS_BL1);
        unsigned long long* key = (unsigned long long*)(ws + WS_KEY1);
        vq_prep_all<<<1344, 256, 0, stream>>>(z, cb, Ah, Al, Bh, Bl, zsq, key);
        vq_gemm32<<<4096, 256, 0, stream>>>(Ah, Al, Bh, Bl, zsq, key, 0);
        vq_extract<<<NQ / 256, 256, 0, stream>>>(key, out);
    } else {
        // 2-pass fallback (12.06 MB): B buffer reused across halves of K.
        f16* Bh = (f16*)(ws + WS_BH);
        f16* Bl = (f16*)(ws + WS_BL2);
        unsigned long long* key = (unsigned long long*)(ws + WS_KEY2);
        vq_prep_az<<<320, 256, 0, stream>>>(z, Ah, Al, zsq, key);
        for (int p = 0; p < 2; ++p) {
            int kofs = p * 4096;
            vq_prep_b<<<512, 256, 0, stream>>>(cb, Bh, Bl, kofs);
            vq_gemm32<<<2048, 256, 0, stream>>>(Ah, Al, Bh, Bl, zsq, key, kofs);
        }
        vq_extract<<<NQ / 256, 256, 0, stream>>>(key, out);
    }
}

// Round 7
// 186.283 us; speedup vs baseline: 1.2241x; 1.2241x over previous
//
#include <hip/hip_runtime.h>
#include <cfloat>
#include <stdint.h>

// VQ argmin via exact-split f16 MFMA GEMM — R27: register-neutral software
// pipeline on the R25 base. R26 (32x32 shape) regressed: MFMA-busy time was
// identical (45us) but the 4-accumulator dependency structure + bigger
// epilogue stretched the wall; shape lever closed. R27 reverts to the R25
// 16x16x32 kernel (gemm 120.5us, MfmaUtil 38%) and attacks the residual
// stall: stage loads are consumed by the same stage's MFMAs with no prefetch
// (no spare regs at the 128/wave cap). Fix: term order T1(av*bh), T3(aw*bh),
// T2(av*bl); after T3 {aw,bh} die -> prefetch next {av',bh'} during T2; after
// T2 {av,bl} die -> prefetch {aw',bl'} during next T1. Live fragments never
// exceed 16x half8 = 64 VGPR (+64 AGPR acc = exactly the 4-blocks/CU line);
// roles ping-pong with period 2 -> K-loop unrolled by 2. Every load gets
// >=16 MFMAs of cover. Numerics: same MFMA set per acc, term order ulp-level
// reorder (R22/R26-class, passes); dist fp32(zsq - acc*2^-12); u64 atomicMin
// (ties impossible). Rest is R25-verbatim.
#define KC 8192
#define NQ 8192
#define DD 256
#define NSTAGE 8

typedef _Float16 f16;
typedef _Float16 half8 __attribute__((ext_vector_type(8)));
typedef float floatx4 __attribute__((ext_vector_type(4)));

// ---- workspace maps ----
#define WS_AH   0
#define WS_AL   4194304
#define WS_BH   8388608
#define WS_BL1  12582912           // 1-pass: Bh/Bl 4MB each
#define WS_KEY1 16777216
#define WS_NEED1 (16777216ull + 65536ull)   // 16.06 MiB (<= every observed ws)
#define WS_BL2  10485760           // 2-pass fallback: Bh/Bl 2MB each
#define WS_KEY2 12582912

// ---- device helpers ----
// B-prep (verified R4..R25 layout): gid = [ntl][s 8][q 4][n 128]; thread packs
// 8 d-values (d = s*32 + q*8 + j) of code (kofs + ntl*128 + n), hi/lo split.
__device__ __forceinline__ void prep_b_body(const float* __restrict__ cb,
                                            f16* __restrict__ Bh, f16* __restrict__ Bl,
                                            int kofs, int gid) {
    int n = gid & 127;
    int q = (gid >> 7) & 3;
    int s = (gid >> 9) & 7;
    int ntl = gid >> 12;
    int K = kofs + ntl * 128 + n;
    int d0 = s * 32 + q * 8;
    const float4 v0 = *(const float4*)(cb + (size_t)K * DD + d0);
    const float4 v1 = *(const float4*)(cb + (size_t)K * DD + d0 + 4);
    float vv[8] = {v0.x, v0.y, v0.z, v0.w, v1.x, v1.y, v1.z, v1.w};
    half8 eh8, el8;
    #pragma unroll
    for (int j = 0; j < 8; ++j) {
        float e = vv[j] * 8192.0f;               // exact pow2 scale
        f16 h = (f16)e;
        eh8[j] = h;
        el8[j] = (f16)(e - (float)h);
    }
    *(half8*)(Bh + (size_t)gid * 8) = eh8;
    *(half8*)(Bl + (size_t)gid * 8) = el8;
}

// A-prep (verified R4..R25 layout, byte-identical granules):
//   gid = ((mt*8+st)*4+q)*256 + r holds z[d=st*32+q*8+j][Q=mt*256+r] hi/lo.
__device__ __forceinline__ void prep_a_vec_body(const float* __restrict__ z,
                                                f16* __restrict__ Ah, f16* __restrict__ Al,
                                                int bid, int tid) {
    const int mt = bid >> 3;
    const int s  = bid & 7;
    const int q  = tid >> 6;
    const int lane = tid & 63;
    const int r0 = lane * 4;
    const int Q0 = mt * 256;
    const int b = Q0 >> 10;
    const int t0 = (Q0 & 1023) + r0;
    const float* zp = z + (size_t)b * (DD * 1024) + t0;
    const int d0 = s * 32 + q * 8;
    float4 v[8];
    #pragma unroll
    for (int j = 0; j < 8; ++j)
        v[j] = *(const float4*)(zp + (size_t)(d0 + j) * 1024);
    const size_t gbase = (((size_t)(mt * 8 + s) * 4 + q) * 256 + r0);
    #pragma unroll
    for (int dq = 0; dq < 4; ++dq) {
        half8 zh8, zl8;
        #pragma unroll
        for (int j = 0; j < 8; ++j) {
            float vv = (dq == 0) ? v[j].x : (dq == 1) ? v[j].y : (dq == 2) ? v[j].z : v[j].w;
            f16 h = (f16)vv;
            zh8[j] = h;
            zl8[j] = (f16)(vv - (float)h);       // exact fp32 residual
        }
        *(half8*)(Ah + (gbase + dq) * 8) = zh8;
        *(half8*)(Al + (gbase + dq) * 8) = zl8;
    }
}

// zsq split across 2 threads/query (exact partial chains of all passers;
// zsq[q] = s0 + s1 identical). Also inits the atomic key array.
__device__ __forceinline__ void zsq2_body(const float* __restrict__ z,
                                          float* __restrict__ zsq,
                                          unsigned long long* __restrict__ key,
                                          int gid) {
    int q = gid >> 1, half = gid & 1;
    int b = q >> 10, t = q & 1023;
    const float* p = z + (size_t)b * (DD * 1024) + t + (size_t)(half * 128) * 1024;
    float s = 0.f;
    #pragma unroll 8
    for (int d = 0; d < 128; ++d) { float v = p[(size_t)d * 1024]; s = fmaf(v, v, s); }
    float so = __shfl_xor(s, 1, 64);             // partner half, same q
    if (half == 0) { zsq[q] = s + so; key[q] = ~0ull; }
}

// ---- fused prep, long poles first:
//   blocks [0,64) zsq+key-init | [64,320) A-vec | [320,1344) B ----
__global__ void vq_prep_all(const float* __restrict__ z, const float* __restrict__ cb,
                            f16* __restrict__ Ah, f16* __restrict__ Al,
                            f16* __restrict__ Bh, f16* __restrict__ Bl,
                            float* __restrict__ zsq, unsigned long long* __restrict__ key) {
    int bid = blockIdx.x;
    int tid = threadIdx.x;
    if (bid < 64) {
        zsq2_body(z, zsq, key, bid * 256 + tid);
    } else if (bid < 320) {
        prep_a_vec_body(z, Ah, Al, bid - 64, tid);
    } else {
        prep_b_body(cb, Bh, Bl, 0, (bid - 320) * 256 + tid);
    }
}

// standalone preps for the 2-pass fallback
__global__ void vq_prep_az(const float* __restrict__ z,
                           f16* __restrict__ Ah, f16* __restrict__ Al,
                           float* __restrict__ zsq, unsigned long long* __restrict__ key) {
    int bid = blockIdx.x;
    if (bid < 64) zsq2_body(z, zsq, key, bid * 256 + threadIdx.x);
    else          prep_a_vec_body(z, Ah, Al, bid - 64, threadIdx.x);
}
__global__ void vq_prep_b(const float* __restrict__ cb,
                          f16* __restrict__ Bh, f16* __restrict__ Bl, int kofs) {
    prep_b_body(cb, Bh, Bl, kofs, blockIdx.x * 256 + threadIdx.x);
}

// 16 MFMAs of one term over the 4x4 accumulator tile
#define TERM16(AF, BF) do {                                                     \
    _Pragma("unroll") for (int _m = 0; _m < 4; ++_m)                            \
      _Pragma("unroll") for (int _n = 0; _n < 4; ++_n)                          \
        acc[_m][_n] = __builtin_amdgcn_mfma_f32_16x16x32_f16(                   \
            AF[_m], BF[_n], acc[_m][_n], 0, 0, 0);                              \
} while (0)

// ---- main GEMM (R27): 128x128 block, 2x2 waves of 64x64, A and B direct
//      from global, NO barriers in the K-loop. Register-neutral pipeline:
//      T1(av*bh), T3(aw*bh), [prefetch av',bh'], T2(av*bl), [prefetch aw',bl']
//      with period-2 slot ping-pong; live fragments fixed at 16 x half8. ----
__global__ __launch_bounds__(256, 4)
void vq_gemm16(const f16* __restrict__ Ah, const f16* __restrict__ Al,
               const f16* __restrict__ Bh, const f16* __restrict__ Bl,
               const float* __restrict__ zsq, unsigned long long* __restrict__ keyp,
               int kofs) {
    // Swizzle (R12/R21-verified): per XCD, 8-ntl B chunks x 8 mh2 A tiles.
    const int flat = blockIdx.x;
    const int xcd = flat & 7;
    const int idx = flat >> 3;
    const int mh2 = xcd * 8 + ((idx >> 3) & 7);     // 0..63, 128-row tile
    const int ntl = (idx >> 6) * 8 + (idx & 7);     // 0..63 / 0..31
    const int tid = threadIdx.x;
    const int lane = tid & 63;
    const int wv = tid >> 6;
    const int wm = wv >> 1, wn = wv & 1;            // 2x2 waves of 64x64
    const int quad = lane >> 4;
    const int l16 = lane & 15;

    __shared__ unsigned long long kbuf[256];        // epilogue merge only

    floatx4 acc[4][4];
    #pragma unroll
    for (int i = 0; i < 4; ++i)
        #pragma unroll
        for (int j = 0; j < 4; ++j) acc[i][j] = (floatx4)0.f;

    const int mt = mh2 >> 1;
    const int r0 = (mh2 & 1) * 128;
    // A fragment address in halfs (byte-identical granules to all passers):
    const size_t abase = ((((size_t)(mt * 8) * 4) + quad) * 256
                          + (size_t)(r0 + wm * 64 + l16)) * 8;
    const f16* Ap  = Ah + abase;
    const f16* Alp = Al + abase;
    const f16* Bpb = Bh + ((size_t)(ntl * 8) * 4 + quad) * 1024 + (size_t)(wn * 64 + l16) * 8;
    const f16* Blb = Bl + ((size_t)(ntl * 8) * 4 + quad) * 1024 + (size_t)(wn * 64 + l16) * 8;

    // Fragment slots: A0/A1 (A-side), B0/B1 (B-side). Even stage roles:
    // av=A0, aw=A1, bh=B0, bl=B1; odd stage: av=A1, aw=A0, bh=B0, bl=B1.
    half8 A0[4], A1[4], B0[4], B1[4];
    #pragma unroll
    for (int i = 0; i < 4; ++i) {
        A0[i] = *(const half8*)(Ap  + (size_t)i * 128);   // av(0)
        A1[i] = *(const half8*)(Alp + (size_t)i * 128);   // aw(0)
        B0[i] = *(const half8*)(Bpb + i * 128);           // bh(0)
        B1[i] = *(const half8*)(Blb + i * 128);           // bl(0)
    }

    #pragma unroll
    for (int su = 0; su < 4; ++su) {
        // ================= even stage s = 2*su =================
        TERM16(A0, B0);                              // T1: av*bh
        TERM16(A1, B0);                              // T3: aw*bh  (frees A1,B0)
        #pragma unroll
        for (int i = 0; i < 4; ++i) {                // prefetch av',bh'
            A1[i] = *(const half8*)(Ap  + 8192 + (size_t)i * 128);
            B0[i] = *(const half8*)(Bpb + 4096 + i * 128);
        }
        TERM16(A0, B1);                              // T2: av*bl  (frees A0,B1)
        #pragma unroll
        for (int i = 0; i < 4; ++i) {                // prefetch aw',bl'
            A0[i] = *(const half8*)(Alp + 8192 + (size_t)i * 128);
            B1[i] = *(const half8*)(Blb + 4096 + i * 128);
        }
        // ================= odd stage s = 2*su+1 (roles swapped) =================
        TERM16(A1, B0);                              // T1: av'*bh'
        TERM16(A0, B0);                              // T3: aw'*bh' (frees A0,B0)
        if (su < 3) {
            #pragma unroll
            for (int i = 0; i < 4; ++i) {            // prefetch av'',bh''
                A0[i] = *(const half8*)(Ap  + 16384 + (size_t)i * 128);
                B0[i] = *(const half8*)(Bpb + 8192 + i * 128);
            }
        }
        TERM16(A1, B1);                              // T2: av'*bl' (frees A1,B1)
        if (su < 3) {
            #pragma unroll
            for (int i = 0; i < 4; ++i) {            // prefetch aw'',bl''
                A1[i] = *(const half8*)(Alp + 16384 + (size_t)i * 128);
                B1[i] = *(const half8*)(Blb + 8192 + i * 128);
            }
            // advance two stages
            Ap += 16384; Alp += 16384; Bpb += 8192; Blb += 8192;
        }
    }

    // ---- epilogue (verified C/D map): dist quantization + 2-way merge +
    //      device-wide atomicMin (== sequential u64-min; ties impossible) ----
    const int kb = kofs + ntl * 128 + wn * 64;
    #pragma unroll
    for (int mi = 0; mi < 4; ++mi) {
        #pragma unroll
        for (int reg = 0; reg < 4; ++reg) {
            int qlocal = wm * 64 + mi * 16 + quad * 4 + reg;   // verified map
            float zq = zsq[mh2 * 128 + qlocal];
            float bd = FLT_MAX; int bk = 0;
            #pragma unroll
            for (int nj = 0; nj < 4; ++nj) {        // ascending k: '<' keeps lowest
                float dd = zq - acc[mi][nj][reg] * 0x1p-12f;  // single fp32 rounding
                int kk = kb + nj * 16 + l16;
                if (dd < bd || (dd == bd && kk < bk)) { bd = dd; bk = kk; }
            }
            #pragma unroll
            for (int mm = 1; mm <= 8; mm <<= 1) {   // 16-lane butterfly, same q
                float od = __shfl_xor(bd, mm, 64);
                int ok = __shfl_xor(bk, mm, 64);
                if (od < bd || (od == bd && ok < bk)) { bd = od; bk = ok; }
            }
            if (l16 == 0)
                kbuf[wn * 128 + qlocal] =
                    ((unsigned long long)__float_as_uint(bd) << 32) | (unsigned int)bk;
        }
    }
    __syncthreads();
    if (tid < 128) {
        unsigned long long k0 = kbuf[tid];
        unsigned long long k1 = kbuf[128 + tid];
        unsigned long long key = (k1 < k0) ? k1 : k0;
        atomicMin(&keyp[mh2 * 128 + tid], key);     // fire-and-forget, no fence
    }
}

__global__ void vq_extract(const unsigned long long* __restrict__ key,
                           int* __restrict__ out) {
    int q = blockIdx.x * 256 + threadIdx.x;
    out[q] = (int)(key[q] & 0xFFFFFFFFull);
}

extern "C" void kernel_launch(void* const* d_in, const int* in_sizes, int n_in,
                              void* d_out, int out_size, void* d_ws, size_t ws_size,
                              hipStream_t stream) {
    const float* z  = (const float*)d_in[0];   // (8, 256, 1024) fp32
    const float* cb = (const float*)d_in[1];   // (8192, 256) fp32
    char* ws = (char*)d_ws;
    f16* Ah = (f16*)(ws + WS_AH);
    f16* Al = (f16*)(ws + WS_AL);
    // zsq parked in d_out (32 KB): read by gemm, overwritten by extract.
    float* zsq = (float*)d_out;
    int* out = (int*)d_out;

    if (ws_size >= WS_NEED1) {
        f16* Bh = (f16*)(ws + WS_BH);
        f16* Bl = (f16*)(ws + WS_BL1);
        unsigned long long* key = (unsigned long long*)(ws + WS_KEY1);
        vq_prep_all<<<1344, 256, 0, stream>>>(z, cb, Ah, Al, Bh, Bl, zsq, key);
        vq_gemm16<<<4096, 256, 0, stream>>>(Ah, Al, Bh, Bl, zsq, key, 0);
        vq_extract<<<NQ / 256, 256, 0, stream>>>(key, out);
    } else {
        // 2-pass fallback (12.06 MB): B buffer reused across halves of K.
        f16* Bh = (f16*)(ws + WS_BH);
        f16* Bl = (f16*)(ws + WS_BL2);
        unsigned long long* key = (unsigned long long*)(ws + WS_KEY2);
        vq_prep_az<<<320, 256, 0, stream>>>(z, Ah, Al, zsq, key);
        for (int p = 0; p < 2; ++p) {
            int kofs = p * 4096;
            vq_prep_b<<<512, 256, 0, stream>>>(cb, Bh, Bl, kofs);
            vq_gemm16<<<2048, 256, 0, stream>>>(Ah, Al, Bh, Bl, zsq, key, kofs);
        }
        vq_extract<<<NQ / 256, 256, 0, stream>>>(key, out);
    }
}